// Round 1
// 326.474 us; speedup vs baseline: 1.0437x; 1.0437x over previous
//
#include <hip/hip_runtime.h>
#include <math.h>

typedef __bf16 bf16;
typedef __bf16 bf16x8 __attribute__((ext_vector_type(8)));
typedef __bf16 bf16x4 __attribute__((ext_vector_type(4)));
typedef float f32x4 __attribute__((ext_vector_type(4)));

// ---------------------------------------------------------------------------
// async global->LDS 16B (direct-to-shared DMA). LDS dest must be
// wave-uniform base + lane*16 — all staging maps below guarantee that.
// ---------------------------------------------------------------------------
__device__ __forceinline__ void ldg_lds16(const bf16* g, bf16* l) {
#if __has_builtin(__builtin_amdgcn_global_load_lds)
    __builtin_amdgcn_global_load_lds(
        (const __attribute__((address_space(1))) void*)g,
        (__attribute__((address_space(3))) void*)l, 16, 0, 0);
#else
    *(bf16x8*)l = *(const bf16x8*)g;
#endif
}

// ---------------------------------------------------------------------------
// cvt_x: fp32 -> bf16, 8 elems/thread, coalesced.
// ---------------------------------------------------------------------------
__global__ void cvt_x(const float* __restrict__ X, bf16* __restrict__ Xb, int total8)
{
    int idx = blockIdx.x * 256 + threadIdx.x;
    if (idx >= total8) return;
    const float* p = X + (size_t)idx * 8;
    f32x4 a = *reinterpret_cast<const f32x4*>(p);
    f32x4 b = *reinterpret_cast<const f32x4*>(p + 4);
    bf16x8 r;
    r[0] = (bf16)a[0]; r[1] = (bf16)a[1]; r[2] = (bf16)a[2]; r[3] = (bf16)a[3];
    r[4] = (bf16)b[0]; r[5] = (bf16)b[1]; r[6] = (bf16)b[2]; r[7] = (bf16)b[3];
    *reinterpret_cast<bf16x8*>(Xb + (size_t)idx * 8) = r;
}

// ---------------------------------------------------------------------------
// cvt_wt: W[K=2048][Ncols] fp32 -> Wt[Ncols][2048] bf16 (transpose via LDS).
// block (32,8); grid (Ncols/32, 2048/32).
// ---------------------------------------------------------------------------
__global__ void cvt_wt(const float* __restrict__ W, bf16* __restrict__ Wt, int Ncols)
{
    __shared__ float t[32][33];
    const int n0 = blockIdx.x * 32, k0 = blockIdx.y * 32;
    const int x = threadIdx.x, y = threadIdx.y;
    #pragma unroll
    for (int i = 0; i < 4; ++i)
        t[y + 8 * i][x] = W[(size_t)(k0 + y + 8 * i) * Ncols + n0 + x];
    __syncthreads();
    #pragma unroll
    for (int i = 0; i < 4; ++i)
        Wt[(size_t)(n0 + y + 8 * i) * 2048 + k0 + x] = (bf16)t[x][y + 8 * i];
}

// ---------------------------------------------------------------------------
// gemm_bt (m97 structure, 128x128, BK=32): retained for the output projection
// (MODE 2), where its 512-block grid fills all CUs (2 blocks/CU).
// ---------------------------------------------------------------------------
template <int MODE>
__global__ __launch_bounds__(256) void gemm_bt(
    const bf16* __restrict__ A, const bf16* __restrict__ Bt,
    void* __restrict__ C0, void* __restrict__ C1, void* __restrict__ C2,
    int M, int N, int K)
{
    __shared__ __align__(16) bf16 As[128 * 32];
    __shared__ __align__(16) bf16 Bs[128 * 32];

    const int tid  = threadIdx.x;
    const int lane = tid & 63;
    const int wave = tid >> 6;
    const int quad = lane >> 4;
    const int l16  = lane & 15;

    const int m0 = blockIdx.y * 128;
    const int n0 = blockIdx.x * 128;
    const int wm = (wave >> 1) * 64;
    const int wn = (wave & 1) * 64;

    f32x4 acc[4][4] = {};

    for (int k0 = 0; k0 < K; k0 += 32) {
        #pragma unroll
        for (int p = 0; p < 2; ++p) {
            int u = p * 256 + tid;
            int row = u >> 2, kc = u & 3;
            ldg_lds16(A  + (size_t)(m0 + row) * K + k0 + kc * 8, &As[u * 8]);
            ldg_lds16(Bt + (size_t)(n0 + row) * K + k0 + kc * 8, &Bs[u * 8]);
        }
        __syncthreads();

        bf16x8 af[4], bfr[4];
        #pragma unroll
        for (int i = 0; i < 4; ++i) {
            af[i]  = *reinterpret_cast<const bf16x8*>(&As[(wm + i * 16 + l16) * 32 + quad * 8]);
            bfr[i] = *reinterpret_cast<const bf16x8*>(&Bs[(wn + i * 16 + l16) * 32 + quad * 8]);
        }
        #pragma unroll
        for (int mi = 0; mi < 4; ++mi)
            #pragma unroll
            for (int ni = 0; ni < 4; ++ni)
                acc[mi][ni] = __builtin_amdgcn_mfma_f32_16x16x32_bf16(
                    af[mi], bfr[ni], acc[mi][ni], 0, 0, 0);
        __syncthreads();
    }

    #pragma unroll
    for (int mi = 0; mi < 4; ++mi) {
        #pragma unroll
        for (int ni = 0; ni < 4; ++ni) {
            const int row = m0 + wm + mi * 16 + quad * 4;
            const int col = n0 + wn + ni * 16 + l16;
            if (MODE == 2) {
                float* C = (float*)C0;
                #pragma unroll
                for (int r = 0; r < 4; ++r)
                    C[(size_t)(row + r) * N + col] = acc[mi][ni][r];
            } else {
                if (n0 < 2048) {
                    bf16* Q = (bf16*)C0;
                    #pragma unroll
                    for (int r = 0; r < 4; ++r)
                        Q[(size_t)(row + r) * 2048 + col] = (bf16)acc[mi][ni][r];
                } else if (n0 < 2560) {
                    bf16* Kb = (bf16*)C1;
                    #pragma unroll
                    for (int r = 0; r < 4; ++r)
                        Kb[(size_t)(row + r) * 512 + (col - 2048)] = (bf16)acc[mi][ni][r];
                } else {
                    bf16* Vt = (bf16*)C2;
                    bf16x4 v;
                    #pragma unroll
                    for (int r = 0; r < 4; ++r) v[r] = (bf16)acc[mi][ni][r];
                    *reinterpret_cast<bf16x4*>(&Vt[(size_t)(col - 2560) * 4096 + row]) = v;
                }
            }
        }
    }
}

// ---------------------------------------------------------------------------
// gemm256_qkv: 256x256 tile, BK=64, 8 waves (2Mx4N), double-buffered 128KB
// LDS, counted-vmcnt pipeline (T3/T4) + read-side XOR swizzle (T2, via
// pre-swizzled global source per rule #21) + setprio around MFMA (T5).
//
// Per K-tile t (buf b = t&1):
//   read all 24 frags of buf[b]  ->  lgkmcnt(0)  ->  s_barrier  (buf free)
//   issue global_load_lds for K-tile t+2 into buf[b]  (8 loads/thread)
//   MFMA (kk=1 half) under setprio(1)
//   s_waitcnt vmcnt(8)   (K-tile t+1 landed; t+2's 8 loads stay in flight)
//   s_barrier
// Raw barriers (no __syncthreads) so the compiler never drains vmcnt(0).
//
// Swizzle: LDS holds logical colbytes = scol ^ ((row&7)<<4). Staging keeps
// the LDS dest linear and permutes the GLOBAL column: kc8 = (u&7)^(row&7)
// (within one 128B line -> coalescing preserved). Reads apply the same
// involution -> each ds_read_b128's 64 lanes spread 8-per-16B-slot across
// all 32 banks (balanced; was a stride-64B pileup).
// ---------------------------------------------------------------------------
__global__ __launch_bounds__(512, 2) void gemm256_qkv(
    const bf16* __restrict__ A, const bf16* __restrict__ Bt,
    bf16* __restrict__ Qo, bf16* __restrict__ Ko, bf16* __restrict__ Vt,
    int K)
{
    __shared__ __align__(16) bf16 smem[2 * 32768];   // 128 KB: [buf][A|B]

    const int tid  = threadIdx.x;
    const int lane = tid & 63;
    const int wave = tid >> 6;
    const int quad = lane >> 4;
    const int l16  = lane & 15;
    const int wm   = wave >> 2;          // 0..1  (M half)
    const int wn   = wave & 3;           // 0..3  (N quarter)

    const int m0 = blockIdx.y * 256;
    const int n0 = blockIdx.x * 256;

    // staging: pass p covers rows [p*64, p*64+64); 8 threads/row, source
    // column chunk pre-swizzled so a linear LDS write realizes the XOR layout.
    int offA[4], offB[4];
    #pragma unroll
    for (int p = 0; p < 4; ++p) {
        int u = p * 512 + tid;
        int row = u >> 3;
        int kc8 = (u & 7) ^ (row & 7);
        offA[p] = (m0 + row) * K + kc8 * 8;
        offB[p] = (n0 + row) * K + kc8 * 8;
    }
    const int dstoff = tid * 8;          // elems; = wave-uniform + lane*16B

    // read-side swizzled column offsets (elements) for kk=0 / kk=1
    const int xv = (l16 & 7) << 4;                 // byte XOR value
    const int c0 = ((quad * 16) ^ xv) >> 1;
    const int c1 = ((64 + quad * 16) ^ xv) >> 1;
    const int rA = (wm * 128 + l16) * 64;          // elem row base, A
    const int rB = (wn * 64 + l16) * 64;           // elem row base, B

    f32x4 acc[8][4] = {};
    const int NT = K >> 6;               // 32

    // prologue: stage K-tiles 0 and 1 (8+8 loads); wait for tile 0 only.
    {
        bf16* d0 = smem;
        bf16* d1 = smem + 32768;
        #pragma unroll
        for (int p = 0; p < 4; ++p) {
            ldg_lds16(A  + offA[p], d0 + p * 4096 + dstoff);
            ldg_lds16(Bt + offB[p], d0 + 16384 + p * 4096 + dstoff);
        }
        #pragma unroll
        for (int p = 0; p < 4; ++p) {
            ldg_lds16(A  + offA[p] + 64, d1 + p * 4096 + dstoff);
            ldg_lds16(Bt + offB[p] + 64, d1 + 16384 + p * 4096 + dstoff);
        }
    }
    asm volatile("s_waitcnt vmcnt(8)" ::: "memory");
    __builtin_amdgcn_sched_barrier(0);
    __builtin_amdgcn_s_barrier();
    __builtin_amdgcn_sched_barrier(0);

    for (int t = 0; t < NT; ++t) {
        const bf16* As = smem + (t & 1) * 32768;
        const bf16* Bs = As + 16384;

        // ---- fragment reads (compiler emits ds_read_b128 + fine lgkmcnt)
        bf16x8 a0[8], b0[4];
        #pragma unroll
        for (int i = 0; i < 8; ++i)
            a0[i] = *(const bf16x8*)(As + rA + i * 1024 + c0);
        #pragma unroll
        for (int i = 0; i < 4; ++i)
            b0[i] = *(const bf16x8*)(Bs + rB + i * 1024 + c0);

        // kk=0 MFMAs (overlap with kk=1 reads below via compiler scheduling)
        #pragma unroll
        for (int mi = 0; mi < 8; ++mi)
            #pragma unroll
            for (int ni = 0; ni < 4; ++ni)
                acc[mi][ni] = __builtin_amdgcn_mfma_f32_16x16x32_bf16(
                    a0[mi], b0[ni], acc[mi][ni], 0, 0, 0);

        bf16x8 a1[8], b1[4];
        #pragma unroll
        for (int i = 0; i < 8; ++i)
            a1[i] = *(const bf16x8*)(As + rA + i * 1024 + c1);
        #pragma unroll
        for (int i = 0; i < 4; ++i)
            b1[i] = *(const bf16x8*)(Bs + rB + i * 1024 + c1);

        // all reads of buf[b] complete -> buffer is free for restaging
        asm volatile("s_waitcnt lgkmcnt(0)" ::: "memory");
        __builtin_amdgcn_sched_barrier(0);
        __builtin_amdgcn_s_barrier();
        __builtin_amdgcn_sched_barrier(0);

        // prefetch K-tile t+2 into the just-freed buffer
        if (t + 2 < NT) {
            bf16* d = smem + (t & 1) * 32768;
            const int koff = (t + 2) * 64;
            #pragma unroll
            for (int p = 0; p < 4; ++p) {
                ldg_lds16(A  + offA[p] + koff, d + p * 4096 + dstoff);
                ldg_lds16(Bt + offB[p] + koff, d + 16384 + p * 4096 + dstoff);
            }
        }

        // kk=1 MFMAs cover the load-issue latency
        __builtin_amdgcn_s_setprio(1);
        #pragma unroll
        for (int mi = 0; mi < 8; ++mi)
            #pragma unroll
            for (int ni = 0; ni < 4; ++ni)
                acc[mi][ni] = __builtin_amdgcn_mfma_f32_16x16x32_bf16(
                    a1[mi], b1[ni], acc[mi][ni], 0, 0, 0);
        __builtin_amdgcn_s_setprio(0);

        // counted wait: K-tile t+1 landed; t+2's 8 loads remain in flight
        if (t + 2 < NT) {
            asm volatile("s_waitcnt vmcnt(8)" ::: "memory");
            __builtin_amdgcn_sched_barrier(0);
            __builtin_amdgcn_s_barrier();
            __builtin_amdgcn_sched_barrier(0);
        } else if (t == NT - 2) {
            asm volatile("s_waitcnt vmcnt(0)" ::: "memory");
            __builtin_amdgcn_sched_barrier(0);
            __builtin_amdgcn_s_barrier();
            __builtin_amdgcn_sched_barrier(0);
        }
        // t == NT-1: fall straight to epilogue (no further LDS reuse)
    }

    // ---- epilogue: QKV split (Q | K | Vt-transposed), same regions as before
    #pragma unroll
    for (int mi = 0; mi < 8; ++mi) {
        #pragma unroll
        for (int ni = 0; ni < 4; ++ni) {
            const int row = m0 + wm * 128 + mi * 16 + quad * 4;
            const int col = n0 + wn * 64 + ni * 16 + l16;
            if (n0 < 2048) {            // Q region (block x = 0..7)
                #pragma unroll
                for (int r = 0; r < 4; ++r)
                    Qo[(size_t)(row + r) * 2048 + col] = (bf16)acc[mi][ni][r];
            } else if (n0 < 2560) {     // K region (block x = 8,9)
                #pragma unroll
                for (int r = 0; r < 4; ++r)
                    Ko[(size_t)(row + r) * 512 + (col - 2048)] = (bf16)acc[mi][ni][r];
            } else {                    // V region -> transposed Vt[d][t]
                bf16x4 v;
                #pragma unroll
                for (int r = 0; r < 4; ++r) v[r] = (bf16)acc[mi][ni][r];
                *reinterpret_cast<bf16x4*>(&Vt[(size_t)(col - 2560) * 4096 + row]) = v;
            }
        }
    }
}

// ---------------------------------------------------------------------------
// RoPE in-place on [T, H, 128] bf16. One thread per (t,h,j), j in 0..63.
// ---------------------------------------------------------------------------
__global__ void rope_kernel(bf16* __restrict__ X, int logH, int total)
{
    int idx = blockIdx.x * 256 + threadIdx.x;
    if (idx >= total) return;
    int j  = idx & 63;
    int th = idx >> 6;
    int t  = th >> logH;

    bf16* p = X + (size_t)th * 128;
    const float NEG_LN1E4_64 = -0.14391155806323211f;  // -ln(10000)/64
    float inv_freq = expf(NEG_LN1E4_64 * (float)j);
    float ang = (float)t * inv_freq;
    float c = cosf(ang), s = sinf(ang);
    float q0 = (float)p[j], q1 = (float)p[j + 64];
    p[j]      = (bf16)(q0 * c - q1 * s);
    p[j + 64] = (bf16)(q1 * c + q0 * s);
}

// ---------------------------------------------------------------------------
// attn_v5: flash attention, sliding window 1024, causal, GQA. (unchanged)
// ---------------------------------------------------------------------------
__global__ __launch_bounds__(256) void attn_v5(
    const bf16* __restrict__ Q, const bf16* __restrict__ K,
    const bf16* __restrict__ Vt, bf16* __restrict__ Y)
{
    const float scale = 0.08838834764831845f;  // 1/sqrt(128)

    __shared__ __align__(16) bf16 Ks[4 * 64 * 32];   // [c][kk][32d]
    __shared__ __align__(16) bf16 Vs[2 * 128 * 32];  // [kc][d][32k]
    __shared__ __align__(16) bf16 Pl[4][16 * 72];    // per-wave P[row][64key]

    const int tid  = threadIdx.x;
    const int lane = tid & 63;
    const int wave = tid >> 6;
    const int quad = lane >> 4;
    const int l16  = lane & 15;

    const int i0  = blockIdx.x * 64;
    const int h   = blockIdx.y;
    const int kvh = h >> 2;
    const int q0  = i0 + wave * 16;
    bf16* Plw = Pl[wave];

    bf16x8 qf[4];
    {
        const bf16* qp = Q + (size_t)(q0 + l16) * 2048 + h * 128 + quad * 8;
        #pragma unroll
        for (int c = 0; c < 4; ++c)
            qf[c] = *reinterpret_cast<const bf16x8*>(qp + c * 32);
    }

    f32x4 o[8] = {};
    float lsum[4] = {0.f, 0.f, 0.f, 0.f};

    const int ks = (i0 >= 1024) ? (i0 - 1024) : 0;
    const int nsteps = (i0 + 64 - ks) >> 6;

    for (int t = 0; t < nsteps; ++t) {
        const int k0 = ks + t * 64;

        #pragma unroll
        for (int p = 0; p < 4; ++p) {
            int u = p * 256 + tid;
            int c = u >> 8, kk = (u >> 2) & 63, q8 = u & 3;
            ldg_lds16(K + (size_t)(k0 + kk) * 512 + kvh * 128 + c * 32 + q8 * 8,
                      &Ks[u * 8]);
        }
        #pragma unroll
        for (int p = 0; p < 4; ++p) {
            int u = p * 256 + tid;
            int kc = u >> 9, d = (u >> 2) & 127, q8 = u & 3;
            ldg_lds16(Vt + (size_t)(kvh * 128 + d) * 4096 + k0 + kc * 32 + q8 * 8,
                      &Vs[u * 8]);
        }
        __syncthreads();

        f32x4 s[4];
        #pragma unroll
        for (int kh = 0; kh < 4; ++kh) {
            f32x4 sv = {};
            #pragma unroll
            for (int c = 0; c < 4; ++c) {
                bf16x8 kf = *reinterpret_cast<const bf16x8*>(
                    &Ks[c * 2048 + (kh * 16 + l16) * 32 + quad * 8]);
                sv = __builtin_amdgcn_mfma_f32_16x16x32_bf16(qf[c], kf, sv, 0, 0, 0);
            }
            s[kh] = sv;
        }

        #pragma unroll
        for (int kh = 0; kh < 4; ++kh) {
            const int key = k0 + kh * 16 + l16;
            #pragma unroll
            for (int r = 0; r < 4; ++r) {
                const int qrow = q0 + quad * 4 + r;
                bool ok = (key <= qrow) && (qrow - key < 1024);
                float pv = ok ? __expf(s[kh][r] * scale) : 0.f;
                lsum[r] += pv;
                Plw[(quad * 4 + r) * 72 + kh * 16 + l16] = (bf16)pv;
            }
        }

        bf16x8 pf0 = *reinterpret_cast<const bf16x8*>(&Plw[l16 * 72 + quad * 8]);
        bf16x8 pf1 = *reinterpret_cast<const bf16x8*>(&Plw[l16 * 72 + 32 + quad * 8]);
        #pragma unroll
        for (int n = 0; n < 8; ++n) {
            bf16x8 v0 = *reinterpret_cast<const bf16x8*>(
                &Vs[(n * 16 + l16) * 32 + quad * 8]);
            bf16x8 v1 = *reinterpret_cast<const bf16x8*>(
                &Vs[4096 + (n * 16 + l16) * 32 + quad * 8]);
            o[n] = __builtin_amdgcn_mfma_f32_16x16x32_bf16(pf0, v0, o[n], 0, 0, 0);
            o[n] = __builtin_amdgcn_mfma_f32_16x16x32_bf16(pf1, v1, o[n], 0, 0, 0);
        }
        __syncthreads();
    }

    #pragma unroll
    for (int r = 0; r < 4; ++r) {
        #pragma unroll
        for (int off = 1; off < 16; off <<= 1)
            lsum[r] += __shfl_xor(lsum[r], off, 64);
    }
    #pragma unroll
    for (int r = 0; r < 4; ++r) {
        int row = q0 + quad * 4 + r;
        float inv = (lsum[r] > 0.f) ? 1.f / lsum[r] : 0.f;
        #pragma unroll
        for (int n = 0; n < 8; ++n)
            Y[(size_t)row * 2048 + h * 128 + n * 16 + l16] = (bf16)(o[n][r] * inv);
    }
}

// ---------------------------------------------------------------------------
extern "C" void kernel_launch(void* const* d_in, const int* in_sizes, int n_in,
                              void* d_out, int out_size, void* d_ws, size_t ws_size,
                              hipStream_t stream)
{
    const float* x  = (const float*)d_in[0];
    const float* Wq = (const float*)d_in[1];
    const float* Wk = (const float*)d_in[2];
    const float* Wv = (const float*)d_in[3];
    const float* Wo = (const float*)d_in[4];
    float* out = (float*)d_out;

    const int T = 4096, DIM = 2048;

    // d_out (32MB fp32) hosts bf16 intermediates, all dead before final GEMM:
    //   [0,16M) Qb [T,2048] | [16M,20M) Kb [T,512] | [20M,24M) Vt [512][T]
    char* po = (char*)d_out;
    bf16* Qb = (bf16*)(po);
    bf16* Kb = (bf16*)(po + (16u << 20));
    bf16* Vtb = (bf16*)(po + (20u << 20));

    // ws (peak 28MB): [0,16M) xb -> later Yb ; [16M,28M) Wqkv^T -> later Wo^T
    char* ws = (char*)d_ws;
    bf16* xb    = (bf16*)(ws);
    bf16* Wqkvt = (bf16*)(ws + (16u << 20));
    bf16* Yb    = (bf16*)(ws);                 // reuses xb (dead after QKV GEMM)
    bf16* Wot   = (bf16*)(ws + (16u << 20));   // reuses Wqkv^T (dead after QKV GEMM)

    // 1. convert x -> bf16
    cvt_x<<<dim3(T * DIM / 8 / 256), 256, 0, stream>>>(x, xb, T * DIM / 8);

    // 2. transpose-convert Wq|Wk|Wv -> Wqkv^T [3072][2048]
    dim3 tb(32, 8);
    cvt_wt<<<dim3(2048 / 32, 64), tb, 0, stream>>>(Wq, Wqkvt, 2048);
    cvt_wt<<<dim3(512 / 32, 64),  tb, 0, stream>>>(Wk, Wqkvt + (size_t)2048 * 2048, 512);
    cvt_wt<<<dim3(512 / 32, 64),  tb, 0, stream>>>(Wv, Wqkvt + (size_t)2560 * 2048, 512);

    // 3. fused QKV GEMM (256x256 deep-pipelined): -> Qb | Kb | Vt
    gemm256_qkv<<<dim3(3072 / 256, T / 256), 512, 0, stream>>>(
        xb, Wqkvt, Qb, Kb, Vtb, DIM);

    // 4. Wo^T (after QKV GEMM frees the region)
    cvt_wt<<<dim3(2048 / 32, 64), tb, 0, stream>>>(Wo, Wot, 2048);

    // 5. RoPE
    int qtot = T * 16 * 64, ktot = T * 4 * 64;
    rope_kernel<<<(qtot + 255) / 256, 256, 0, stream>>>(Qb, 4, qtot);
    rope_kernel<<<(ktot + 255) / 256, 256, 0, stream>>>(Kb, 2, ktot);

    // 6. attention
    attn_v5<<<dim3(T / 64, 16), 256, 0, stream>>>(Qb, Kb, Vtb, Yb);

    // 7. output projection: [4096,2048] x [2048,2048]^T -> out (fp32)
    gemm_bt<2><<<dim3(2048 / 128, T / 128), 256, 0, stream>>>(
        Yb, Wot, out, nullptr, nullptr, T, 2048, DIM);
}